// Round 14
// baseline (184.460 us; speedup 1.0000x reference)
//
#include <hip/hip_runtime.h>

typedef unsigned short ushort_t;
typedef unsigned int uint_t;
typedef __bf16 bf16x8 __attribute__((ext_vector_type(8)));
typedef float f32x16 __attribute__((ext_vector_type(16)));
typedef float f32x4 __attribute__((ext_vector_type(4)));
typedef float f32x2 __attribute__((ext_vector_type(2)));
typedef short short8v __attribute__((ext_vector_type(8)));
typedef short short4v __attribute__((ext_vector_type(4)));

__device__ __forceinline__ ushort_t f2b(float f) {
    union { float f; uint_t i; } v; v.f = f;
    uint_t u = v.i;
    u += 0x7fffu + ((u >> 16) & 1u);
    return (ushort_t)(u >> 16);
}
union V8 { short8v v; uint_t d[4]; };
union S8 { short8v v; short4v h[2]; };
union CV2 { uint2 u2; f32x2 f; };
// single-instruction RTNE bf16 pair pack (R11-verified bit-identical)
__device__ __forceinline__ uint_t cvtpk(float lo, float hi) {
    uint_t r;
    asm("v_cvt_pk_bf16_f32 %0, %1, %2" : "=v"(r) : "v"(lo), "v"(hi));
    return r;
}
// packed-fp32 blend (R13-verified): per dword, f32x2 pk_fma chain + cvt_pk.
__device__ __forceinline__ uint4 blend_pack(short8v a, short8v b, short8v c, short8v d,
                                            float w00, float w01, float w10, float w11) {
    V8 ua, ub, uc, ud;
    ua.v = a; ub.v = b; uc.v = c; ud.v = d;
    f32x2 W00 = {w00, w00}, W01 = {w01, w01}, W10 = {w10, w10}, W11 = {w11, w11};
    uint_t pk[4];
    #pragma unroll
    for (int i = 0; i < 4; ++i) {
        CV2 c00, c01, c10, c11;
        c00.u2 = make_uint2(ua.d[i] << 16, ua.d[i] & 0xffff0000u);
        c01.u2 = make_uint2(ub.d[i] << 16, ub.d[i] & 0xffff0000u);
        c10.u2 = make_uint2(uc.d[i] << 16, uc.d[i] & 0xffff0000u);
        c11.u2 = make_uint2(ud.d[i] << 16, ud.d[i] & 0xffff0000u);
        f32x2 s = W00 * c00.f + W01 * c01.f + W10 * c10.f + W11 * c11.f;
        pk[i] = cvtpk(s.x, s.y);
    }
    uint4 r; r.x = pk[0]; r.y = pk[1]; r.z = pk[2]; r.w = pk[3];
    return r;
}
__device__ __forceinline__ void calc_corners(float py, float px, int chbase,
    float& w00, float& w01, float& w10, float& w11,
    int& o00, int& o01, int& o10, int& o11)
{
    float y0f = floorf(py), x0f = floorf(px);
    float wy = py - y0f, wx = px - x0f;
    int iy0 = (int)y0f, ix0 = (int)x0f;
    float fy0 = (iy0 >= 0 && iy0 < 64) ? 1.f : 0.f;
    float fy1 = (iy0 >= -1 && iy0 < 63) ? 1.f : 0.f;
    float fx0 = (ix0 >= 0 && ix0 < 64) ? 1.f : 0.f;
    float fx1 = (ix0 >= -1 && ix0 < 63) ? 1.f : 0.f;
    int cy0 = min(max(iy0, 0), 63), cy1 = min(max(iy0 + 1, 0), 63);
    int cx0 = min(max(ix0, 0), 63), cx1 = min(max(ix0 + 1, 0), 63);
    w00 = (1.f - wy) * (1.f - wx) * fy0 * fx0;
    w01 = (1.f - wy) * wx * fy0 * fx1;
    w10 = wy * (1.f - wx) * fy1 * fx0;
    w11 = wy * wx * fy1 * fx1;
    o00 = (cy0 * 64 + cx0) * 128 + chbase;
    o01 = (cy0 * 64 + cx1) * 128 + chbase;
    o10 = (cy1 * 64 + cx0) * 128 + chbase;
    o11 = (cy1 * 64 + cx1) * 128 + chbase;
}

// ---------------- xt: NCHW fp32 -> NHWC bf16  (+ all weight packing) ----------------
// wA layout (fragment-major for LINEAR LDS staging in fused):
//   index = p*16384 + f*512 + lane*8 + e,  f = (ks*2+mh)*2+half
//   value = deform_w[cout = mh*64+half*32+(lane&31)][ch = ks*16+((lane>>5)<<3)+e][p]
__global__ __launch_bounds__(256) void xt_prep_kernel(
    const float* __restrict__ x, ushort_t* __restrict__ xt,
    const float* __restrict__ deform_w,   // (128,128,3,3)
    const float* __restrict__ offset_w,   // (18,128,3,3)
    const float* __restrict__ gamma,
    const float* __restrict__ beta,
    const float* __restrict__ rmean,
    const float* __restrict__ rvar,
    ushort_t* __restrict__ wA,    // fragment-major, see above
    ushort_t* __restrict__ wOb,   // [32 (18 used)][k=tap*128+c] bf16
    float* __restrict__ scale,
    float* __restrict__ shift)
{
    __shared__ __align__(16) ushort_t tile[64 * 132];
    int braw = blockIdx.x;
    int b = ((braw & 7) << 7) + (braw >> 3);   // XCD k -> n {2k,2k+1}
    int n = b >> 6, h = b & 63;
    int t = threadIdx.x;

    int i = braw * 256 + t;
    if (i < 147456) {
        int e    = i & 7;
        int l    = (i >> 3) & 63;
        int half = (i >> 9) & 1;
        int mh   = (i >> 10) & 1;
        int ks   = (i >> 11) & 7;
        int p    = i >> 14;
        int cout = mh * 64 + half * 32 + (l & 31);
        int ch   = ks * 16 + ((l >> 5) << 3) + e;
        wA[i] = f2b(deform_w[cout * 1152 + ch * 9 + p]);
    }
    if (i < 36864) {
        int row = i / 1152;
        int k = i - row * 1152;
        int tap = k >> 7, c = k & 127;
        wOb[i] = (row < 18) ? f2b(offset_w[row * 1152 + c * 9 + tap]) : (ushort_t)0;
    }
    if (i < 128) {
        float sc = gamma[i] * rsqrtf(rvar[i] + 1e-5f);
        scale[i] = sc;
        shift[i] = beta[i] - rmean[i] * sc;
    }

    // x[n][c][h][w] -> tile[w][c];  thread: channel c = t&127, w-half = t>>7
    {
        int c = t & 127, half = t >> 7;
        const float* src = x + (((n * 128 + c) * 64 + h) << 6) + half * 32;
        float4 f[8];
        #pragma unroll
        for (int j = 0; j < 8; ++j) f[j] = *(const float4*)(src + j * 4);
        #pragma unroll
        for (int j = 0; j < 8; ++j) {
            int w = half * 32 + j * 4;
            tile[(w + 0) * 132 + c] = f2b(f[j].x);
            tile[(w + 1) * 132 + c] = f2b(f[j].y);
            tile[(w + 2) * 132 + c] = f2b(f[j].z);
            tile[(w + 3) * 132 + c] = f2b(f[j].w);
        }
    }
    __syncthreads();
    #pragma unroll
    for (int it = 0; it < 4; ++it) {
        int idx = it * 2048 + t * 8;
        int ww = idx >> 7, cc = idx & 127;
        S8 u;
        u.h[0] = *(const short4v*)(&tile[ww * 132 + cc]);
        u.h[1] = *(const short4v*)(&tile[ww * 132 + cc + 4]);
        *(short8v*)(xt + ((n * 64 + h) * 64 + ww) * 128 + cc) = u.v;
    }
}

// ---------------- fused: offset-conv (MFMA) + bilinear sample + GEMM + BN + SiLU ----
// R13 structure (96.4us: A via global_load_lds, granule-coalesced gathers,
// pk_fma+cvt_pk blend, single-buffered S0, 2 barriers/p). Two micro-changes:
// (1) gather-prefetch issued AFTER barrier1 (was: just before it, where the
//     compiler's pre-barrier vmcnt(0) drained it with zero cover; now it
//     retires under the MFMA cluster and drains at barrier2),
// (2) s_setprio(1) around the MFMA cluster (T5: 3 independent blocks/CU are
//     at different phases -> scheduler can favor the MFMA-issuing wave).
// Tripwires: FETCH ~10.5 MB, WRITE = 32768 KB, VGPR <= 80, absmax 0.03125.
__global__ __launch_bounds__(256, 3) void fused_kernel(
    const ushort_t* __restrict__ xt,      // (16,64,64,128) bf16
    const ushort_t* __restrict__ wA,      // fragment-major [p][f][lane][8]
    const ushort_t* __restrict__ wOb,     // [32][1152] bf16
    const float* __restrict__ offset_b,   // (18,)
    const float* __restrict__ scale,
    const float* __restrict__ shift,
    float* __restrict__ out)              // (16,128,64,64) fp32
{
    __shared__ __align__(16) char smem[53760];
    ushort_t* S0   = (ushort_t*)smem;              // [64][128] bf16 (phase 3)
    ushort_t* Alds = (ushort_t*)(smem + 16384);    // [32][512]B frag-major A
    float*    posb = (float*)(smem + 49152);       // [18][64] fp32
    ushort_t* sxp  = (ushort_t*)smem;              // [3][66][128] (phases 1-2 alias)

    int braw = blockIdx.x;
    int b = ((braw & 7) << 7) + (braw >> 3);       // XCD slab swizzle
    int n = b >> 6, ho = b & 63;
    int t = threadIdx.x;
    int lane = t & 63;
    int wv = __builtin_amdgcn_readfirstlane(t >> 6);

    const ushort_t* xn = xt + n * (64 * 64 * 128);

    // ---- phase 1: stage rows ho-1..ho+1, col-padded (66), granule-swizzled ----
    for (int i = t; i < 3168; i += 256) {
        int r = (i >= 2112) ? 2 : ((i >= 1056) ? 1 : 0);
        int rem = i - r * 1056;
        int colp = rem >> 4, g = rem & 15;
        int row = ho - 1 + r, col = colp - 1;
        short8v v = {0, 0, 0, 0, 0, 0, 0, 0};
        if (row >= 0 && row < 64 && col >= 0 && col < 64)
            v = *(const short8v*)(xn + (row * 64 + col) * 128 + g * 8);
        int gg = g ^ (colp & 15);
        *(short8v*)(sxp + (r * 66 + colp) * 128 + gg * 8) = v;
    }
    __syncthreads();

    // ---- phase 2: offset conv via mfma 16x16x32 (M=32pad, N=16/wave, K=1152) ----
    {
        f32x4 acc2[2];
        #pragma unroll
        for (int mt = 0; mt < 2; ++mt)
            #pragma unroll
            for (int r = 0; r < 4; ++r) acc2[mt][r] = 0.f;

        int m = lane & 15, kq = lane >> 4;
        int pixq = wv * 16 + m;
        #pragma unroll
        for (int ks = 0; ks < 36; ++ks) {
            const int tap = ks >> 2, cq = ks & 3;
            const int krow = tap / 3, kx = tap % 3;     // constants after unroll
            bf16x8 a0 = *(const bf16x8*)(wOb + m * 1152 + tap * 128 + cq * 32 + kq * 8);
            bf16x8 a1 = *(const bf16x8*)(wOb + (16 + m) * 1152 + tap * 128 + cq * 32 + kq * 8);
            int colp = pixq + kx;
            int gg = (cq * 4 + kq) ^ (colp & 15);
            bf16x8 bf = *(const bf16x8*)(sxp + (krow * 66 + colp) * 128 + gg * 8);
            acc2[0] = __builtin_amdgcn_mfma_f32_16x16x32_bf16(a0, bf, acc2[0], 0, 0, 0);
            acc2[1] = __builtin_amdgcn_mfma_f32_16x16x32_bf16(a1, bf, acc2[1], 0, 0, 0);
        }
        __syncthreads();     // all sxp reads done before posb (aliases sxp tail)
        #pragma unroll
        for (int mt = 0; mt < 2; ++mt)
            #pragma unroll
            for (int r = 0; r < 4; ++r) {
                int oc = mt * 16 + kq * 4 + r;
                if (oc < 18) {
                    float v = acc2[mt][r] + offset_b[oc];
                    int pp = oc >> 1;
                    v += (oc & 1) ? (float)(pp % 3 - 1 + pixq) : (float)(pp / 3 - 1 + ho);
                    posb[oc * 64 + pixq] = v;
                }
            }
    }
    __syncthreads();   // posb visible; sxp dead -> S0/Alds regions reusable

    // ---- phase 3: deform sampling + MFMA GEMM; A staged in LDS; 2 barriers/p ----
    int chbase = wv * 32;
    int mh = wv >> 1, nh = wv & 1;
    int sub = lane >> 2, gj = lane & 3;   // pixel-subgroup / granule of this lane

    f32x16 acc[2];
    #pragma unroll
    for (int mt = 0; mt < 2; ++mt)
        #pragma unroll
        for (int r = 0; r < 16; ++r) acc[mt][r] = 0.f;

    float w00[4], w01[4], w10[4], w11[4];
    short8v v00[4], v01[4], v10[4], v11[4];

    // stage A(0): 8 x global_load_lds per wave, 1KB each, linear dest
    {
        const ushort_t* src = wA + (wv * 8) * 512 + lane * 8;
        #pragma unroll
        for (int c = 0; c < 8; ++c) {
            __builtin_amdgcn_global_load_lds(
                (const __attribute__((address_space(1))) void*)(src + c * 512),
                (__attribute__((address_space(3))) void*)(Alds + (wv * 8 + c) * 512),
                16, 0, 0);
        }
    }

    // prologue p=0: 4 pixel-groups; lanes 4k..4k+3 load contiguous 64B per corner
    #pragma unroll
    for (int i = 0; i < 4; ++i) {
        int q = i * 16 + sub;
        int o00, o01, o10, o11;
        calc_corners(posb[q], posb[64 + q], chbase,
                     w00[i], w01[i], w10[i], w11[i], o00, o01, o10, o11);
        v00[i] = *(const short8v*)(xn + o00 + gj * 8);
        v01[i] = *(const short8v*)(xn + o01 + gj * 8);
        v10[i] = *(const short8v*)(xn + o10 + gj * 8);
        v11[i] = *(const short8v*)(xn + o11 + gj * 8);
    }

    for (int p = 0; p < 9; ++p) {
        // blend current p into S0 (single buffer; barrier2 of p-1 cleared readers)
        #pragma unroll
        for (int i = 0; i < 4; ++i) {
            uint4 pk = blend_pack(v00[i], v01[i], v10[i], v11[i],
                                  w00[i], w01[i], w10[i], w11[i]);
            int q = i * 16 + sub;
            int gg = (wv * 4 + gj) ^ (q & 15);
            *(uint4*)(S0 + q * 128 + gg * 8) = pk;
        }

        __syncthreads();   // barrier1: S0 stores visible; A(p) staging drained

        if (p < 8) {   // prefetch next p's gathers AFTER barrier1: they retire
                       // under the MFMA cluster and drain at barrier2 (cover
                       // ~400+ cyc vs zero when issued pre-barrier1)
            #pragma unroll
            for (int i = 0; i < 4; ++i) {
                int q = i * 16 + sub;
                int o00, o01, o10, o11;
                calc_corners(posb[(2 * p + 2) * 64 + q], posb[(2 * p + 3) * 64 + q],
                             chbase, w00[i], w01[i], w10[i], w11[i], o00, o01, o10, o11);
                v00[i] = *(const short8v*)(xn + o00 + gj * 8);
                v01[i] = *(const short8v*)(xn + o01 + gj * 8);
                v10[i] = *(const short8v*)(xn + o10 + gj * 8);
                v11[i] = *(const short8v*)(xn + o11 + gj * 8);
            }
        }

        int pixb = nh * 32 + (lane & 31);
        __builtin_amdgcn_s_setprio(1);
        #pragma unroll
        for (int ks = 0; ks < 8; ++ks) {
            // fragment-major A from LDS: 64 lanes x 16B contiguous, conflict-free
            bf16x8 a0 = *(const bf16x8*)(Alds + ((ks * 2 + mh) * 2 + 0) * 512 + lane * 8);
            bf16x8 a1 = *(const bf16x8*)(Alds + ((ks * 2 + mh) * 2 + 1) * 512 + lane * 8);
            int gg = (ks * 2 + (lane >> 5)) ^ (pixb & 15);
            bf16x8 bfrag = *(const bf16x8*)(S0 + pixb * 128 + gg * 8);
            acc[0] = __builtin_amdgcn_mfma_f32_32x32x16_bf16(a0, bfrag, acc[0], 0, 0, 0);
            acc[1] = __builtin_amdgcn_mfma_f32_32x32x16_bf16(a1, bfrag, acc[1], 0, 0, 0);
        }
        __builtin_amdgcn_s_setprio(0);

        __syncthreads();   // barrier2: MFMA readers of S0 + Alds done

        if (p < 8) {       // stage A(p+1); drains at next iteration's barrier1
            const ushort_t* src = wA + (p + 1) * 16384 + (wv * 8) * 512 + lane * 8;
            #pragma unroll
            for (int c = 0; c < 8; ++c) {
                __builtin_amdgcn_global_load_lds(
                    (const __attribute__((address_space(1))) void*)(src + c * 512),
                    (__attribute__((address_space(3))) void*)(Alds + (wv * 8 + c) * 512),
                    16, 0, 0);
            }
        }
    }

    // ---- epilogue: BN + SiLU ----
    int pixb = nh * 32 + (lane & 31);
    #pragma unroll
    for (int mt = 0; mt < 2; ++mt) {
        #pragma unroll
        for (int r = 0; r < 16; ++r) {
            int cout = mh * 64 + mt * 32 + (r & 3) + 8 * (r >> 2) + 4 * (lane >> 5);
            float v = acc[mt][r] * scale[cout] + shift[cout];
            float rr = v / (1.f + __expf(-v));
            out[((n * 128 + cout) * 64 + ho) * 64 + pixb] = rr;
        }
    }
}

extern "C" void kernel_launch(void* const* d_in, const int* in_sizes, int n_in,
                              void* d_out, int out_size, void* d_ws, size_t ws_size,
                              hipStream_t stream) {
    const float* x        = (const float*)d_in[0];
    const float* offset_w = (const float*)d_in[1];
    const float* offset_b = (const float*)d_in[2];
    const float* deform_w = (const float*)d_in[3];
    const float* gamma    = (const float*)d_in[4];
    const float* beta     = (const float*)d_in[5];
    const float* rmean    = (const float*)d_in[6];
    const float* rvar     = (const float*)d_in[7];

    char* ws = (char*)d_ws;
    ushort_t* xt    = (ushort_t*)(ws);               // 16,777,216 B
    ushort_t* wA    = (ushort_t*)(ws + 16777216);    //    294,912 B
    ushort_t* wOb   = (ushort_t*)(ws + 17072128);    //     73,728 B
    float*    scale = (float*)(ws + 17145856);       //        512 B
    float*    shift = (float*)(ws + 17146368);       //        512 B
    float*    out   = (float*)d_out;

    hipLaunchKernelGGL(xt_prep_kernel, dim3(1024), dim3(256), 0, stream,
                       x, xt, deform_w, offset_w, gamma, beta, rmean, rvar,
                       wA, wOb, scale, shift);
    hipLaunchKernelGGL(fused_kernel, dim3(1024), dim3(256), 0, stream,
                       xt, wA, wOb, offset_b, scale, shift, out);
}

// Round 15
// 181.331 us; speedup vs baseline: 1.0173x; 1.0173x over previous
//
#include <hip/hip_runtime.h>

typedef unsigned short ushort_t;
typedef unsigned int uint_t;
typedef __bf16 bf16x8 __attribute__((ext_vector_type(8)));
typedef float f32x16 __attribute__((ext_vector_type(16)));
typedef float f32x4 __attribute__((ext_vector_type(4)));
typedef float f32x2 __attribute__((ext_vector_type(2)));
typedef short short8v __attribute__((ext_vector_type(8)));
typedef short short4v __attribute__((ext_vector_type(4)));

__device__ __forceinline__ ushort_t f2b(float f) {
    union { float f; uint_t i; } v; v.f = f;
    uint_t u = v.i;
    u += 0x7fffu + ((u >> 16) & 1u);
    return (ushort_t)(u >> 16);
}
union V8 { short8v v; uint_t d[4]; };
union S8 { short8v v; short4v h[2]; };
union CV2 { uint2 u2; f32x2 f; };
// single-instruction RTNE bf16 pair pack (R11-verified bit-identical)
__device__ __forceinline__ uint_t cvtpk(float lo, float hi) {
    uint_t r;
    asm("v_cvt_pk_bf16_f32 %0, %1, %2" : "=v"(r) : "v"(lo), "v"(hi));
    return r;
}
// packed-fp32 blend (R13-verified): per dword, f32x2 pk_fma chain + cvt_pk.
__device__ __forceinline__ uint4 blend_pack(short8v a, short8v b, short8v c, short8v d,
                                            float w00, float w01, float w10, float w11) {
    V8 ua, ub, uc, ud;
    ua.v = a; ub.v = b; uc.v = c; ud.v = d;
    f32x2 W00 = {w00, w00}, W01 = {w01, w01}, W10 = {w10, w10}, W11 = {w11, w11};
    uint_t pk[4];
    #pragma unroll
    for (int i = 0; i < 4; ++i) {
        CV2 c00, c01, c10, c11;
        c00.u2 = make_uint2(ua.d[i] << 16, ua.d[i] & 0xffff0000u);
        c01.u2 = make_uint2(ub.d[i] << 16, ub.d[i] & 0xffff0000u);
        c10.u2 = make_uint2(uc.d[i] << 16, uc.d[i] & 0xffff0000u);
        c11.u2 = make_uint2(ud.d[i] << 16, ud.d[i] & 0xffff0000u);
        f32x2 s = W00 * c00.f + W01 * c01.f + W10 * c10.f + W11 * c11.f;
        pk[i] = cvtpk(s.x, s.y);
    }
    uint4 r; r.x = pk[0]; r.y = pk[1]; r.z = pk[2]; r.w = pk[3];
    return r;
}
__device__ __forceinline__ void calc_corners(float py, float px, int chbase,
    float& w00, float& w01, float& w10, float& w11,
    int& o00, int& o01, int& o10, int& o11)
{
    float y0f = floorf(py), x0f = floorf(px);
    float wy = py - y0f, wx = px - x0f;
    int iy0 = (int)y0f, ix0 = (int)x0f;
    float fy0 = (iy0 >= 0 && iy0 < 64) ? 1.f : 0.f;
    float fy1 = (iy0 >= -1 && iy0 < 63) ? 1.f : 0.f;
    float fx0 = (ix0 >= 0 && ix0 < 64) ? 1.f : 0.f;
    float fx1 = (ix0 >= -1 && ix0 < 63) ? 1.f : 0.f;
    int cy0 = min(max(iy0, 0), 63), cy1 = min(max(iy0 + 1, 0), 63);
    int cx0 = min(max(ix0, 0), 63), cx1 = min(max(ix0 + 1, 0), 63);
    w00 = (1.f - wy) * (1.f - wx) * fy0 * fx0;
    w01 = (1.f - wy) * wx * fy0 * fx1;
    w10 = wy * (1.f - wx) * fy1 * fx0;
    w11 = wy * wx * fy1 * fx1;
    o00 = (cy0 * 64 + cx0) * 128 + chbase;
    o01 = (cy0 * 64 + cx1) * 128 + chbase;
    o10 = (cy1 * 64 + cx0) * 128 + chbase;
    o11 = (cy1 * 64 + cx1) * 128 + chbase;
}

// ---------------- xt: NCHW fp32 -> NHWC bf16  (+ all weight packing) ----------------
// wA layout (fragment-major for LINEAR LDS staging in fused):
//   index = p*16384 + f*512 + lane*8 + e,  f = (ks*2+mh)*2+half
//   value = deform_w[cout = mh*64+half*32+(lane&31)][ch = ks*16+((lane>>5)<<3)+e][p]
__global__ __launch_bounds__(256) void xt_prep_kernel(
    const float* __restrict__ x, ushort_t* __restrict__ xt,
    const float* __restrict__ deform_w,   // (128,128,3,3)
    const float* __restrict__ offset_w,   // (18,128,3,3)
    const float* __restrict__ gamma,
    const float* __restrict__ beta,
    const float* __restrict__ rmean,
    const float* __restrict__ rvar,
    ushort_t* __restrict__ wA,    // fragment-major, see above
    ushort_t* __restrict__ wOb,   // [32 (18 used)][k=tap*128+c] bf16
    float* __restrict__ scale,
    float* __restrict__ shift)
{
    __shared__ __align__(16) ushort_t tile[64 * 132];
    int braw = blockIdx.x;
    int b = ((braw & 7) << 7) + (braw >> 3);   // XCD k -> n {2k,2k+1}
    int n = b >> 6, h = b & 63;
    int t = threadIdx.x;

    int i = braw * 256 + t;
    if (i < 147456) {
        int e    = i & 7;
        int l    = (i >> 3) & 63;
        int half = (i >> 9) & 1;
        int mh   = (i >> 10) & 1;
        int ks   = (i >> 11) & 7;
        int p    = i >> 14;
        int cout = mh * 64 + half * 32 + (l & 31);
        int ch   = ks * 16 + ((l >> 5) << 3) + e;
        wA[i] = f2b(deform_w[cout * 1152 + ch * 9 + p]);
    }
    if (i < 36864) {
        int row = i / 1152;
        int k = i - row * 1152;
        int tap = k >> 7, c = k & 127;
        wOb[i] = (row < 18) ? f2b(offset_w[row * 1152 + c * 9 + tap]) : (ushort_t)0;
    }
    if (i < 128) {
        float sc = gamma[i] * rsqrtf(rvar[i] + 1e-5f);
        scale[i] = sc;
        shift[i] = beta[i] - rmean[i] * sc;
    }

    // x[n][c][h][w] -> tile[w][c];  thread: channel c = t&127, w-half = t>>7
    {
        int c = t & 127, half = t >> 7;
        const float* src = x + (((n * 128 + c) * 64 + h) << 6) + half * 32;
        float4 f[8];
        #pragma unroll
        for (int j = 0; j < 8; ++j) f[j] = *(const float4*)(src + j * 4);
        #pragma unroll
        for (int j = 0; j < 8; ++j) {
            int w = half * 32 + j * 4;
            tile[(w + 0) * 132 + c] = f2b(f[j].x);
            tile[(w + 1) * 132 + c] = f2b(f[j].y);
            tile[(w + 2) * 132 + c] = f2b(f[j].z);
            tile[(w + 3) * 132 + c] = f2b(f[j].w);
        }
    }
    __syncthreads();
    #pragma unroll
    for (int it = 0; it < 4; ++it) {
        int idx = it * 2048 + t * 8;
        int ww = idx >> 7, cc = idx & 127;
        S8 u;
        u.h[0] = *(const short4v*)(&tile[ww * 132 + cc]);
        u.h[1] = *(const short4v*)(&tile[ww * 132 + cc + 4]);
        *(short8v*)(xt + ((n * 64 + h) * 64 + ww) * 128 + cc) = u.v;
    }
}

// ---------------- fused: offset-conv (MFMA) + bilinear sample + GEMM + BN + SiLU ----
// FINAL = R13 config (96.4us measured best; 2.7x vs session start):
//   - granule-coalesced bilinear gathers (R7: lanes 4k..4k+3 load one
//     contiguous 64B corner line -> 16 TA transactions/instr, no redundant
//     line touches; -38us)
//   - A-operands staged per-p via global_load_lds, fragment-major, consumed
//     by conflict-free ds_read_b128 (R12: A off the TA pipe; -41us)
//   - v_cvt_pk_bf16_f32 pack + v_pk_fma_f32 blend (R11/R13: -4.6us)
//   - single-buffered S0, 2 barriers/p
// Dead ends measured this session (do not retry): occupancy/residency
// (R1/R3/R4/R10 x4), issue-order scheduling + setprio (R6/R9/R14 x3),
// fragment-major global A (R8, spills). At 96us no pipe >~80%; the residual
// is the barrier-skeleton latency chain. Further LDS-read/MFMA reduction
// needs 64x64-per-wave tiles (~164 VGPR -> spill zone). Structural floor.
// Tripwires: FETCH ~10.4 MB, WRITE = 32768 KB, VGPR ~72, absmax 0.03125.
__global__ __launch_bounds__(256, 3) void fused_kernel(
    const ushort_t* __restrict__ xt,      // (16,64,64,128) bf16
    const ushort_t* __restrict__ wA,      // fragment-major [p][f][lane][8]
    const ushort_t* __restrict__ wOb,     // [32][1152] bf16
    const float* __restrict__ offset_b,   // (18,)
    const float* __restrict__ scale,
    const float* __restrict__ shift,
    float* __restrict__ out)              // (16,128,64,64) fp32
{
    __shared__ __align__(16) char smem[53760];
    ushort_t* S0   = (ushort_t*)smem;              // [64][128] bf16 (phase 3)
    ushort_t* Alds = (ushort_t*)(smem + 16384);    // [32][512]B frag-major A
    float*    posb = (float*)(smem + 49152);       // [18][64] fp32
    ushort_t* sxp  = (ushort_t*)smem;              // [3][66][128] (phases 1-2 alias)

    int braw = blockIdx.x;
    int b = ((braw & 7) << 7) + (braw >> 3);       // XCD slab swizzle
    int n = b >> 6, ho = b & 63;
    int t = threadIdx.x;
    int lane = t & 63;
    int wv = __builtin_amdgcn_readfirstlane(t >> 6);

    const ushort_t* xn = xt + n * (64 * 64 * 128);

    // ---- phase 1: stage rows ho-1..ho+1, col-padded (66), granule-swizzled ----
    for (int i = t; i < 3168; i += 256) {
        int r = (i >= 2112) ? 2 : ((i >= 1056) ? 1 : 0);
        int rem = i - r * 1056;
        int colp = rem >> 4, g = rem & 15;
        int row = ho - 1 + r, col = colp - 1;
        short8v v = {0, 0, 0, 0, 0, 0, 0, 0};
        if (row >= 0 && row < 64 && col >= 0 && col < 64)
            v = *(const short8v*)(xn + (row * 64 + col) * 128 + g * 8);
        int gg = g ^ (colp & 15);
        *(short8v*)(sxp + (r * 66 + colp) * 128 + gg * 8) = v;
    }
    __syncthreads();

    // ---- phase 2: offset conv via mfma 16x16x32 (M=32pad, N=16/wave, K=1152) ----
    {
        f32x4 acc2[2];
        #pragma unroll
        for (int mt = 0; mt < 2; ++mt)
            #pragma unroll
            for (int r = 0; r < 4; ++r) acc2[mt][r] = 0.f;

        int m = lane & 15, kq = lane >> 4;
        int pixq = wv * 16 + m;
        #pragma unroll
        for (int ks = 0; ks < 36; ++ks) {
            const int tap = ks >> 2, cq = ks & 3;
            const int krow = tap / 3, kx = tap % 3;     // constants after unroll
            bf16x8 a0 = *(const bf16x8*)(wOb + m * 1152 + tap * 128 + cq * 32 + kq * 8);
            bf16x8 a1 = *(const bf16x8*)(wOb + (16 + m) * 1152 + tap * 128 + cq * 32 + kq * 8);
            int colp = pixq + kx;
            int gg = (cq * 4 + kq) ^ (colp & 15);
            bf16x8 bf = *(const bf16x8*)(sxp + (krow * 66 + colp) * 128 + gg * 8);
            acc2[0] = __builtin_amdgcn_mfma_f32_16x16x32_bf16(a0, bf, acc2[0], 0, 0, 0);
            acc2[1] = __builtin_amdgcn_mfma_f32_16x16x32_bf16(a1, bf, acc2[1], 0, 0, 0);
        }
        __syncthreads();     // all sxp reads done before posb (aliases sxp tail)
        #pragma unroll
        for (int mt = 0; mt < 2; ++mt)
            #pragma unroll
            for (int r = 0; r < 4; ++r) {
                int oc = mt * 16 + kq * 4 + r;
                if (oc < 18) {
                    float v = acc2[mt][r] + offset_b[oc];
                    int pp = oc >> 1;
                    v += (oc & 1) ? (float)(pp % 3 - 1 + pixq) : (float)(pp / 3 - 1 + ho);
                    posb[oc * 64 + pixq] = v;
                }
            }
    }
    __syncthreads();   // posb visible; sxp dead -> S0/Alds regions reusable

    // ---- phase 3: deform sampling + MFMA GEMM; A staged in LDS; 2 barriers/p ----
    int chbase = wv * 32;
    int mh = wv >> 1, nh = wv & 1;
    int sub = lane >> 2, gj = lane & 3;   // pixel-subgroup / granule of this lane

    f32x16 acc[2];
    #pragma unroll
    for (int mt = 0; mt < 2; ++mt)
        #pragma unroll
        for (int r = 0; r < 16; ++r) acc[mt][r] = 0.f;

    float w00[4], w01[4], w10[4], w11[4];
    short8v v00[4], v01[4], v10[4], v11[4];

    // stage A(0): 8 x global_load_lds per wave, 1KB each, linear dest
    {
        const ushort_t* src = wA + (wv * 8) * 512 + lane * 8;
        #pragma unroll
        for (int c = 0; c < 8; ++c) {
            __builtin_amdgcn_global_load_lds(
                (const __attribute__((address_space(1))) void*)(src + c * 512),
                (__attribute__((address_space(3))) void*)(Alds + (wv * 8 + c) * 512),
                16, 0, 0);
        }
    }

    // prologue p=0: 4 pixel-groups; lanes 4k..4k+3 load contiguous 64B per corner
    #pragma unroll
    for (int i = 0; i < 4; ++i) {
        int q = i * 16 + sub;
        int o00, o01, o10, o11;
        calc_corners(posb[q], posb[64 + q], chbase,
                     w00[i], w01[i], w10[i], w11[i], o00, o01, o10, o11);
        v00[i] = *(const short8v*)(xn + o00 + gj * 8);
        v01[i] = *(const short8v*)(xn + o01 + gj * 8);
        v10[i] = *(const short8v*)(xn + o10 + gj * 8);
        v11[i] = *(const short8v*)(xn + o11 + gj * 8);
    }

    for (int p = 0; p < 9; ++p) {
        // blend current p into S0 (single buffer; barrier2 of p-1 cleared readers)
        #pragma unroll
        for (int i = 0; i < 4; ++i) {
            uint4 pk = blend_pack(v00[i], v01[i], v10[i], v11[i],
                                  w00[i], w01[i], w10[i], w11[i]);
            int q = i * 16 + sub;
            int gg = (wv * 4 + gj) ^ (q & 15);
            *(uint4*)(S0 + q * 128 + gg * 8) = pk;
        }

        if (p < 8) {   // prefetch next p's gathers (positions from stable posb)
            #pragma unroll
            for (int i = 0; i < 4; ++i) {
                int q = i * 16 + sub;
                int o00, o01, o10, o11;
                calc_corners(posb[(2 * p + 2) * 64 + q], posb[(2 * p + 3) * 64 + q],
                             chbase, w00[i], w01[i], w10[i], w11[i], o00, o01, o10, o11);
                v00[i] = *(const short8v*)(xn + o00 + gj * 8);
                v01[i] = *(const short8v*)(xn + o01 + gj * 8);
                v10[i] = *(const short8v*)(xn + o10 + gj * 8);
                v11[i] = *(const short8v*)(xn + o11 + gj * 8);
            }
        }

        __syncthreads();   // barrier1: S0 stores visible; A(p) staging drained

        int pixb = nh * 32 + (lane & 31);
        #pragma unroll
        for (int ks = 0; ks < 8; ++ks) {
            // fragment-major A from LDS: 64 lanes x 16B contiguous, conflict-free
            bf16x8 a0 = *(const bf16x8*)(Alds + ((ks * 2 + mh) * 2 + 0) * 512 + lane * 8);
            bf16x8 a1 = *(const bf16x8*)(Alds + ((ks * 2 + mh) * 2 + 1) * 512 + lane * 8);
            int gg = (ks * 2 + (lane >> 5)) ^ (pixb & 15);
            bf16x8 bfrag = *(const bf16x8*)(S0 + pixb * 128 + gg * 8);
            acc[0] = __builtin_amdgcn_mfma_f32_32x32x16_bf16(a0, bfrag, acc[0], 0, 0, 0);
            acc[1] = __builtin_amdgcn_mfma_f32_32x32x16_bf16(a1, bfrag, acc[1], 0, 0, 0);
        }

        __syncthreads();   // barrier2: MFMA readers of S0 + Alds done

        if (p < 8) {       // stage A(p+1); drains at next iteration's barrier1
            const ushort_t* src = wA + (p + 1) * 16384 + (wv * 8) * 512 + lane * 8;
            #pragma unroll
            for (int c = 0; c < 8; ++c) {
                __builtin_amdgcn_global_load_lds(
                    (const __attribute__((address_space(1))) void*)(src + c * 512),
                    (__attribute__((address_space(3))) void*)(Alds + (wv * 8 + c) * 512),
                    16, 0, 0);
            }
        }
    }

    // ---- epilogue: BN + SiLU ----
    int pixb = nh * 32 + (lane & 31);
    #pragma unroll
    for (int mt = 0; mt < 2; ++mt) {
        #pragma unroll
        for (int r = 0; r < 16; ++r) {
            int cout = mh * 64 + mt * 32 + (r & 3) + 8 * (r >> 2) + 4 * (lane >> 5);
            float v = acc[mt][r] * scale[cout] + shift[cout];
            float rr = v / (1.f + __expf(-v));
            out[((n * 128 + cout) * 64 + ho) * 64 + pixb] = rr;
        }
    }
}

extern "C" void kernel_launch(void* const* d_in, const int* in_sizes, int n_in,
                              void* d_out, int out_size, void* d_ws, size_t ws_size,
                              hipStream_t stream) {
    const float* x        = (const float*)d_in[0];
    const float* offset_w = (const float*)d_in[1];
    const float* offset_b = (const float*)d_in[2];
    const float* deform_w = (const float*)d_in[3];
    const float* gamma    = (const float*)d_in[4];
    const float* beta     = (const float*)d_in[5];
    const float* rmean    = (const float*)d_in[6];
    const float* rvar     = (const float*)d_in[7];

    char* ws = (char*)d_ws;
    ushort_t* xt    = (ushort_t*)(ws);               // 16,777,216 B
    ushort_t* wA    = (ushort_t*)(ws + 16777216);    //    294,912 B
    ushort_t* wOb   = (ushort_t*)(ws + 17072128);    //     73,728 B
    float*    scale = (float*)(ws + 17145856);       //        512 B
    float*    shift = (float*)(ws + 17146368);       //        512 B
    float*    out   = (float*)d_out;

    hipLaunchKernelGGL(xt_prep_kernel, dim3(1024), dim3(256), 0, stream,
                       x, xt, deform_w, offset_w, gamma, beta, rmean, rvar,
                       wA, wOb, scale, shift);
    hipLaunchKernelGGL(fused_kernel, dim3(1024), dim3(256), 0, stream,
                       xt, wA, wOb, offset_b, scale, shift, out);
}